// Round 1
// baseline (10083.241 us; speedup 1.0000x reference)
//
#include <hip/hip_runtime.h>
#include <hip/hip_fp16.h>

// Problem dims
#define H     1024
#define NIN   128
#define NOUT  128
#define BATCH 64
#define SEQ   512
#define MROWS (BATCH * SEQ)   // 32768

typedef _Float16 half8  __attribute__((ext_vector_type(8)));
typedef _Float16 half4v __attribute__((ext_vector_type(4)));
typedef float    f32x4  __attribute__((ext_vector_type(4)));

// ---------------------------------------------------------------------------
// f32 -> f16 conversion (vectorized, 4 elems/thread)
// ---------------------------------------------------------------------------
__global__ void cvt16_kernel(const float* __restrict__ src,
                             _Float16* __restrict__ dst, int n4) {
  int i = blockIdx.x * blockDim.x + threadIdx.x;
  if (i < n4) {
    float4 v = reinterpret_cast<const float4*>(src)[i];
    half4v h = {(_Float16)v.x, (_Float16)v.y, (_Float16)v.z, (_Float16)v.w};
    *reinterpret_cast<half4v*>(dst + (size_t)i * 4) = h;
  }
}

// ---------------------------------------------------------------------------
// combined biases + zero (h double-buffers + barrier counters); ws is poisoned
// 0xAA before every timed call so this must run every call.
// ---------------------------------------------------------------------------
__global__ void init_misc_kernel(const float* __restrict__ b_ih0,
                                 const float* __restrict__ b_hh0,
                                 const float* __restrict__ b_ih1,
                                 const float* __restrict__ b_hh1,
                                 float* __restrict__ bias0,
                                 float* __restrict__ bias1,
                                 unsigned* __restrict__ zero_base,
                                 int zero_words) {
  int i = blockIdx.x * blockDim.x + threadIdx.x;
  if (i < H) {
    bias0[i] = b_ih0[i] + b_hh0[i];
    bias1[i] = b_ih1[i] + b_hh1[i];
  }
  for (int j = i; j < zero_words; j += gridDim.x * blockDim.x) zero_base[j] = 0u;
}

// ---------------------------------------------------------------------------
// Generic f16 MFMA GEMM, C[m][n] = sum_k A[m][k]*B[n][k] + bias[n]  (fp32 out)
// BM=BN=128, BK=32; 256 threads = 4 waves in 2x2, each wave 64x64 (4x4 frags).
// LDS tiles padded +8 f16 per row to spread banks.
// ---------------------------------------------------------------------------
__global__ __launch_bounds__(256) void gemm_f16_kernel(
    const _Float16* __restrict__ A, const _Float16* __restrict__ B,
    const float* __restrict__ bias, float* __restrict__ C,
    int M, int N, int K) {
  __shared__ _Float16 As[128][40];
  __shared__ _Float16 Bs[128][40];
  const int m0 = blockIdx.x * 128;
  const int n0 = blockIdx.y * 128;
  const int tid = threadIdx.x;
  const int wave = tid >> 6, lane = tid & 63;
  const int wm = (wave >> 1) * 64, wn = (wave & 1) * 64;
  const int fr = lane & 15;          // frag row/col within 16
  const int kg = (lane >> 4) * 8;    // contiguous 8 f16 along K per lane

  f32x4 acc[4][4] = {};
  for (int k0 = 0; k0 < K; k0 += 32) {
    __syncthreads();
    // stage 128x32 f16 tiles of A and B (512 chunks of 8 f16 each)
    for (int c = tid; c < 512; c += 256) {
      int row = c >> 2, ko = (c & 3) * 8;
      *reinterpret_cast<half8*>(&As[row][ko]) =
          *reinterpret_cast<const half8*>(&A[(size_t)(m0 + row) * K + k0 + ko]);
      *reinterpret_cast<half8*>(&Bs[row][ko]) =
          *reinterpret_cast<const half8*>(&B[(size_t)(n0 + row) * K + k0 + ko]);
    }
    __syncthreads();
    half8 af[4], bf[4];
#pragma unroll
    for (int i = 0; i < 4; ++i)
      af[i] = *reinterpret_cast<const half8*>(&As[wm + i * 16 + fr][kg]);
#pragma unroll
    for (int j = 0; j < 4; ++j)
      bf[j] = *reinterpret_cast<const half8*>(&Bs[wn + j * 16 + fr][kg]);
#pragma unroll
    for (int i = 0; i < 4; ++i)
#pragma unroll
      for (int j = 0; j < 4; ++j)
        acc[i][j] = __builtin_amdgcn_mfma_f32_16x16x32_f16(af[i], bf[j],
                                                           acc[i][j], 0, 0, 0);
  }
  // epilogue: D row = 4*(lane>>4)+reg, col = lane&15
  const int lr = (lane >> 4) * 4, lc = lane & 15;
#pragma unroll
  for (int j = 0; j < 4; ++j) {
    int n = n0 + wn + j * 16 + lc;
    float bn = bias ? bias[n] : 0.0f;
#pragma unroll
    for (int i = 0; i < 4; ++i) {
      int m = m0 + wm + i * 16 + lr;
#pragma unroll
      for (int r = 0; r < 4; ++r)
        C[(size_t)(m + r) * N + n] = acc[i][j][r] + bn;
    }
  }
}

// ---------------------------------------------------------------------------
// Recurrent scan. 16 clusters x 16 WGs; cluster = blockIdx & 15 (same-XCD
// under round-robin dispatch; correctness is placement-independent thanks to
// agent-scope acquire/release). Each cluster owns 4 batch rows. Each WG owns
// 64 output columns (4 waves x 16 cols), W_hh slice lives in VGPRs as f16
// B-fragments. Per step: D = h @ W^T via mfma_f32_16x16x32_f16 (A rows 0..3
// real, rest zero), add xp, tanh, write f16 h_next, counter barrier.
// ---------------------------------------------------------------------------
#define NCLUST 16
#define CWGS   16
#define GB     4

__global__ __launch_bounds__(256, 1) void scan_kernel(
    const float* __restrict__ xp,      // [BATCH][SEQ][H] fp32
    const _Float16* __restrict__ W16,  // [H][H] row = out col, contiguous K
    _Float16* __restrict__ hbuf,       // [NCLUST][2][GB][H] f16 (zeroed)
    unsigned* __restrict__ ctr,        // [NCLUST*64] (zeroed)
    _Float16* __restrict__ hs_out,     // layer0: [BATCH][SEQ][H] f16, else null
    float* __restrict__ h_last)        // layer1: [BATCH][H] f32, else null
{
  const int blk = blockIdx.x;
  const int cluster = blk & (NCLUST - 1);
  const int rank = blk >> 4;
  const int wave = threadIdx.x >> 6;
  const int lane = threadIdx.x & 63;
  const int col = rank * 64 + wave * 16 + (lane & 15);
  const int kg8 = (lane >> 4) * 8;
  const int rb = lane & 15;

  // W_hh slice -> registers (32 k-tiles of 32, 8 contiguous f16 per lane)
  half8 wfrag[32];
#pragma unroll
  for (int kt = 0; kt < 32; ++kt)
    wfrag[kt] = *reinterpret_cast<const half8*>(
        &W16[(size_t)col * H + kt * 32 + kg8]);

  _Float16* hme = hbuf + (size_t)cluster * (2 * GB * H);
  unsigned* myctr = ctr + cluster * 64;
  const int b0 = cluster * GB;

  for (int t = 0; t < SEQ; ++t) {
    const _Float16* hcur = hme + (t & 1) * (GB * H);
    _Float16* hnxt = hme + ((t + 1) & 1) * (GB * H);

    // prefetch xp for this step (only lanes 0..15 consume it)
    float xpv[GB];
    if (lane < 16) {
#pragma unroll
      for (int r = 0; r < GB; ++r)
        xpv[r] = xp[((size_t)(b0 + r) * SEQ + t) * H + col];
    }

    f32x4 acc[4] = {};
#pragma unroll
    for (int kt = 0; kt < 32; ++kt) {
      half8 a = {};
      if (rb < GB)
        a = *reinterpret_cast<const half8*>(&hcur[rb * H + kt * 32 + kg8]);
      acc[kt & 3] = __builtin_amdgcn_mfma_f32_16x16x32_f16(a, wfrag[kt],
                                                           acc[kt & 3], 0, 0, 0);
    }
    f32x4 s = acc[0] + acc[1];
    s += acc[2];
    s += acc[3];

    if (lane < 16) {
#pragma unroll
      for (int r = 0; r < GB; ++r) {
        float hv = tanhf(s[r] + xpv[r]);
        if (hs_out)
          hs_out[((size_t)(b0 + r) * SEQ + t) * H + col] = (_Float16)hv;
        if (t < SEQ - 1)
          hnxt[r * H + col] = (_Float16)hv;
        else if (h_last)
          h_last[(size_t)(b0 + r) * H + col] = hv;
      }
    }

    if (t < SEQ - 1) {
      __syncthreads();  // drains this WG's vmem (h stores reach L2)
      if (threadIdx.x == 0) {
        __hip_atomic_fetch_add(myctr, 1u, __ATOMIC_RELEASE,
                               __HIP_MEMORY_SCOPE_AGENT);
        unsigned tgt = (unsigned)(CWGS * (t + 1));
        while (__hip_atomic_load(myctr, __ATOMIC_RELAXED,
                                 __HIP_MEMORY_SCOPE_AGENT) < tgt) {}
        (void)__hip_atomic_load(myctr, __ATOMIC_ACQUIRE,
                                __HIP_MEMORY_SCOPE_AGENT);
      }
      __syncthreads();
    }
  }
}

// ---------------------------------------------------------------------------
// Final FC: out[b][n] = h_last[b] . W_fc[n] + b_fc[n], one wave per output.
// ---------------------------------------------------------------------------
__global__ __launch_bounds__(256) void fc_kernel(
    const float* __restrict__ h_last, const float* __restrict__ W_fc,
    const float* __restrict__ b_fc, float* __restrict__ out) {
  const int wave = threadIdx.x >> 6, lane = threadIdx.x & 63;
  const int o = blockIdx.x * 4 + wave;  // 0..8191
  const int b = o >> 7, n = o & 127;
  const float* hr = h_last + (size_t)b * H;
  const float* wr = W_fc + (size_t)n * H;
  float s = 0.0f;
  for (int k = lane; k < H; k += 64) s += hr[k] * wr[k];
#pragma unroll
  for (int off = 32; off; off >>= 1) s += __shfl_down(s, off);
  if (lane == 0) out[o] = s + b_fc[n];
}

// ---------------------------------------------------------------------------
extern "C" void kernel_launch(void* const* d_in, const int* in_sizes, int n_in,
                              void* d_out, int out_size, void* d_ws,
                              size_t ws_size, hipStream_t stream) {
  (void)in_sizes; (void)n_in; (void)out_size; (void)ws_size;
  const float* x     = (const float*)d_in[0];
  const float* W_ih0 = (const float*)d_in[1];
  const float* b_ih0 = (const float*)d_in[2];
  const float* W_hh0 = (const float*)d_in[3];
  const float* b_hh0 = (const float*)d_in[4];
  const float* W_ih1 = (const float*)d_in[5];
  const float* b_ih1 = (const float*)d_in[6];
  const float* W_hh1 = (const float*)d_in[7];
  const float* b_hh1 = (const float*)d_in[8];
  const float* W_fc  = (const float*)d_in[9];
  const float* b_fc  = (const float*)d_in[10];
  float* out = (float*)d_out;

  char* ws = (char*)d_ws;
  size_t off = 0;
  auto carve = [&](size_t bytes) {
    char* p = ws + off;
    off += (bytes + 255) & ~(size_t)255;
    return p;
  };
  float*    xpbuf   = (float*)   carve((size_t)MROWS * H * 4);  // 134 MB
  _Float16* hs0_16  = (_Float16*)carve((size_t)MROWS * H * 2);  //  67 MB
  _Float16* x16     = (_Float16*)carve((size_t)MROWS * NIN * 2);
  _Float16* wih0_16 = (_Float16*)carve((size_t)H * NIN * 2);
  _Float16* whh0_16 = (_Float16*)carve((size_t)H * H * 2);
  _Float16* wih1_16 = (_Float16*)carve((size_t)H * H * 2);
  _Float16* whh1_16 = (_Float16*)carve((size_t)H * H * 2);
  float*    bias0   = (float*)   carve(H * 4);
  float*    bias1   = (float*)   carve(H * 4);
  // zero region: [h16_0 | h16_1 | ctr0 | ctr1] contiguous
  _Float16* h16_0   = (_Float16*)carve((size_t)NCLUST * 2 * GB * H * 2);
  _Float16* h16_1   = (_Float16*)carve((size_t)NCLUST * 2 * GB * H * 2);
  unsigned* ctr0    = (unsigned*)carve(NCLUST * 64 * 4);
  unsigned* ctr1    = (unsigned*)carve(NCLUST * 64 * 4);
  float*    h_lastp = (float*)   carve((size_t)BATCH * H * 4);

  const int zero_words =
      (int)(((size_t)NCLUST * 2 * GB * H * 2 * 2 + NCLUST * 64 * 4 * 2) / 4);

  // 1. biases + zero h/ctr
  init_misc_kernel<<<(zero_words + 255) / 256, 256, 0, stream>>>(
      b_ih0, b_hh0, b_ih1, b_hh1, bias0, bias1, (unsigned*)h16_0, zero_words);

  // 2. f16 conversions
  cvt16_kernel<<<(MROWS * NIN / 4 + 255) / 256, 256, 0, stream>>>(x, x16,
                                                                  MROWS * NIN / 4);
  cvt16_kernel<<<(H * NIN / 4 + 255) / 256, 256, 0, stream>>>(W_ih0, wih0_16,
                                                              H * NIN / 4);
  cvt16_kernel<<<(H * H / 4 + 255) / 256, 256, 0, stream>>>(W_hh0, whh0_16,
                                                            H * H / 4);
  cvt16_kernel<<<(H * H / 4 + 255) / 256, 256, 0, stream>>>(W_ih1, wih1_16,
                                                            H * H / 4);
  cvt16_kernel<<<(H * H / 4 + 255) / 256, 256, 0, stream>>>(W_hh1, whh1_16,
                                                            H * H / 4);

  // 3. xp0 = x @ W_ih0^T + (b_ih0 + b_hh0)
  {
    dim3 grid(MROWS / 128, H / 128);
    int M = MROWS, N = H, K = NIN;
    gemm_f16_kernel<<<grid, 256, 0, stream>>>(x16, wih0_16, bias0, xpbuf, M, N, K);
  }

  // 4. layer-0 scan (cooperative: co-residency for spin barriers)
  {
    const float* xp_p = xpbuf; const _Float16* w_p = whh0_16;
    _Float16* hb_p = h16_0; unsigned* c_p = ctr0;
    _Float16* hs_p = hs0_16; float* hl_p = nullptr;
    void* args[] = {&xp_p, &w_p, &hb_p, &c_p, &hs_p, &hl_p};
    hipLaunchCooperativeKernel((const void*)scan_kernel, dim3(256), dim3(256),
                               args, 0, stream);
  }

  // 5. xp1 = hs0 @ W_ih1^T + (b_ih1 + b_hh1)   (reuses xpbuf)
  {
    dim3 grid(MROWS / 128, H / 128);
    int M = MROWS, N = H, K = H;
    gemm_f16_kernel<<<grid, 256, 0, stream>>>(hs0_16, wih1_16, bias1, xpbuf, M, N, K);
  }

  // 6. layer-1 scan (keeps only final h)
  {
    const float* xp_p = xpbuf; const _Float16* w_p = whh1_16;
    _Float16* hb_p = h16_1; unsigned* c_p = ctr1;
    _Float16* hs_p = nullptr; float* hl_p = h_lastp;
    void* args[] = {&xp_p, &w_p, &hb_p, &c_p, &hs_p, &hl_p};
    hipLaunchCooperativeKernel((const void*)scan_kernel, dim3(256), dim3(256),
                               args, 0, stream);
  }

  // 7. out = h_last @ W_fc^T + b_fc
  fc_kernel<<<BATCH * NOUT / 4, 256, 0, stream>>>(h_lastp, W_fc, b_fc, out);
}

// Round 2
// 3627.597 us; speedup vs baseline: 2.7796x; 2.7796x over previous
//
#include <hip/hip_runtime.h>
#include <hip/hip_fp16.h>

// Problem dims
#define H     1024
#define NIN   128
#define NOUT  128
#define BATCH 64
#define SEQ   512
#define MROWS (BATCH * SEQ)   // 32768

typedef _Float16 half8  __attribute__((ext_vector_type(8)));
typedef _Float16 half4v __attribute__((ext_vector_type(4)));
typedef float    f32x4  __attribute__((ext_vector_type(4)));
typedef unsigned long long u64;

// ---------------------------------------------------------------------------
// f32 -> f16 conversion (vectorized, 4 elems/thread)
// ---------------------------------------------------------------------------
__global__ void cvt16_kernel(const float* __restrict__ src,
                             _Float16* __restrict__ dst, int n4) {
  int i = blockIdx.x * blockDim.x + threadIdx.x;
  if (i < n4) {
    float4 v = reinterpret_cast<const float4*>(src)[i];
    half4v h = {(_Float16)v.x, (_Float16)v.y, (_Float16)v.z, (_Float16)v.w};
    *reinterpret_cast<half4v*>(dst + (size_t)i * 4) = h;
  }
}

// ---------------------------------------------------------------------------
// combined biases + zero (h double-buffers + flag words); ws is poisoned
// 0xAA before every timed call so this must run every call.
// ---------------------------------------------------------------------------
__global__ void init_misc_kernel(const float* __restrict__ b_ih0,
                                 const float* __restrict__ b_hh0,
                                 const float* __restrict__ b_ih1,
                                 const float* __restrict__ b_hh1,
                                 float* __restrict__ bias0,
                                 float* __restrict__ bias1,
                                 unsigned* __restrict__ zero_base,
                                 int zero_words) {
  int i = blockIdx.x * blockDim.x + threadIdx.x;
  if (i < H) {
    bias0[i] = b_ih0[i] + b_hh0[i];
    bias1[i] = b_ih1[i] + b_hh1[i];
  }
  for (int j = i; j < zero_words; j += gridDim.x * blockDim.x) zero_base[j] = 0u;
}

// ---------------------------------------------------------------------------
// Generic f16 MFMA GEMM, C[m][n] = sum_k A[m][k]*B[n][k] + bias[n]  (fp32 out)
// (unchanged from R1 — passed; not the bottleneck)
// ---------------------------------------------------------------------------
__global__ __launch_bounds__(256) void gemm_f16_kernel(
    const _Float16* __restrict__ A, const _Float16* __restrict__ B,
    const float* __restrict__ bias, float* __restrict__ C,
    int M, int N, int K) {
  __shared__ _Float16 As[128][40];
  __shared__ _Float16 Bs[128][40];
  const int m0 = blockIdx.x * 128;
  const int n0 = blockIdx.y * 128;
  const int tid = threadIdx.x;
  const int wave = tid >> 6, lane = tid & 63;
  const int wm = (wave >> 1) * 64, wn = (wave & 1) * 64;
  const int fr = lane & 15;
  const int kg = (lane >> 4) * 8;

  f32x4 acc[4][4] = {};
  for (int k0 = 0; k0 < K; k0 += 32) {
    __syncthreads();
    for (int c = tid; c < 512; c += 256) {
      int row = c >> 2, ko = (c & 3) * 8;
      *reinterpret_cast<half8*>(&As[row][ko]) =
          *reinterpret_cast<const half8*>(&A[(size_t)(m0 + row) * K + k0 + ko]);
      *reinterpret_cast<half8*>(&Bs[row][ko]) =
          *reinterpret_cast<const half8*>(&B[(size_t)(n0 + row) * K + k0 + ko]);
    }
    __syncthreads();
    half8 af[4], bf[4];
#pragma unroll
    for (int i = 0; i < 4; ++i)
      af[i] = *reinterpret_cast<const half8*>(&As[wm + i * 16 + fr][kg]);
#pragma unroll
    for (int j = 0; j < 4; ++j)
      bf[j] = *reinterpret_cast<const half8*>(&Bs[wn + j * 16 + fr][kg]);
#pragma unroll
    for (int i = 0; i < 4; ++i)
#pragma unroll
      for (int j = 0; j < 4; ++j)
        acc[i][j] = __builtin_amdgcn_mfma_f32_16x16x32_f16(af[i], bf[j],
                                                           acc[i][j], 0, 0, 0);
  }
  const int lr = (lane >> 4) * 4, lc = lane & 15;
#pragma unroll
  for (int j = 0; j < 4; ++j) {
    int n = n0 + wn + j * 16 + lc;
    float bn = bias ? bias[n] : 0.0f;
#pragma unroll
    for (int i = 0; i < 4; ++i) {
      int m = m0 + wm + i * 16 + lr;
#pragma unroll
      for (int r = 0; r < 4; ++r)
        C[(size_t)(m + r) * N + n] = acc[i][j][r] + bn;
    }
  }
}

// ---------------------------------------------------------------------------
// Recurrent scan, fence-free sync version.
//
// 16 clusters x 16 WGs (cluster = blk & 15 -> all WGs of a cluster share
// blk%8, i.e. one XCD under round-robin; correctness does NOT depend on it:
// all cross-WG traffic uses relaxed SYSTEM-scope (sc0 sc1) ops that meet at
// the device-coherent point). Each cluster owns GB=4 batch rows; each WG owns
// 64 output columns (wave owns 16). W_hh slice lives in VGPRs as the MFMA
// *A* operand (full 16 rows used); h is the B operand (4 of 16 rows valid,
// garbage lands in discarded D columns). D: row=(lane>>4)*4+reg = out-col,
// col=lane&15 = batch row -> packed 8B h stores, float4 xp loads.
//
// Sync per step: plain-ish stores -> s_waitcnt vmcnt(0) -> per-WG flag word
// (relaxed system store). Consumers poll 16 flags with one coalesced 64B
// load + ballot. NO acquire/release fences => no buffer_wbl2/buffer_inv
// L2-maintenance storms (the R1 10us/step killer).
// ---------------------------------------------------------------------------
#define NCLUST 16
#define CWGS   16
#define GB     4

__global__ __launch_bounds__(256, 1) void scan_kernel(
    const float* __restrict__ xp,      // [BATCH][SEQ][H] fp32
    const _Float16* __restrict__ W16,  // [H][H] row = out col, contiguous K
    _Float16* __restrict__ hbuf,       // [NCLUST][2][GB][H] f16 (zeroed)
    unsigned* __restrict__ flags,      // [NCLUST][64] (zeroed)
    _Float16* __restrict__ hs_out,     // layer0: [BATCH][SEQ][H] f16, else null
    float* __restrict__ h_last)        // layer1: [BATCH][H] f32, else null
{
  __shared__ _Float16 lds_h[GB][1024 + 8];   // +16B row pad vs bank conflicts

  const int blk = blockIdx.x;
  const int cluster = blk & (NCLUST - 1);
  const int rank = blk >> 4;
  const int wave = threadIdx.x >> 6;
  const int lane = threadIdx.x & 63;
  const int fr = lane & 15;
  const int kg8 = (lane >> 4) * 8;
  const int wcol = rank * 64 + wave * 16;       // wave's 16-col tile base
  const int colb = wcol + ((lane >> 4) << 2);   // this lane's 4 out cols
  const int rb = lane & 15;                     // batch row (valid if <GB)
  const bool act = rb < GB;

  // W_hh A-fragment slice -> registers (32 k-tiles, 16B each = 128 VGPR)
  half8 wfrag[32];
#pragma unroll
  for (int kt = 0; kt < 32; ++kt)
    wfrag[kt] = *reinterpret_cast<const half8*>(
        &W16[(size_t)(wcol + fr) * H + kt * 32 + kg8]);

  _Float16* hme = hbuf + (size_t)cluster * (2 * GB * H);
  unsigned* myflags = flags + cluster * 64;
  const int b0 = cluster * GB;

  for (int t = 0; t < SEQ; ++t) {
    // xp prefetch for this step (h-independent: issues before the flag spin,
    // HBM latency hides under the poll)
    float4 xpv = {0.f, 0.f, 0.f, 0.f};
    if (act)
      xpv = *reinterpret_cast<const float4*>(
          &xp[((size_t)(b0 + rb) * SEQ + t) * H + colb]);

    // wait until all 16 producer flags reach t (output of step t-1 visible)
    if (t > 0) {
      const unsigned tgt = (unsigned)t;
      while (true) {
        unsigned f = tgt;
        if (lane < CWGS)
          f = __hip_atomic_load(&myflags[lane], __ATOMIC_RELAXED,
                                __HIP_MEMORY_SCOPE_SYSTEM);
        if (__ballot(f >= tgt) == ~0ull) break;
      }
      asm volatile("" ::: "memory");  // compiler barrier: no hoist across poll
    }

    // stage h(t) (8KB) into LDS: 256 thr x 4 x 8B system-scope loads
    const u64* hsrc = reinterpret_cast<const u64*>(hme + (t & 1) * (GB * H));
#pragma unroll
    for (int i = 0; i < 4; ++i) {
      u64 v = __hip_atomic_load(&hsrc[i * 256 + threadIdx.x], __ATOMIC_RELAXED,
                                __HIP_MEMORY_SCOPE_SYSTEM);
      *reinterpret_cast<u64*>(&lds_h[i][threadIdx.x * 4]) = v;
    }
    __syncthreads();

    f32x4 acc[4] = {};
#pragma unroll
    for (int kt = 0; kt < 32; ++kt) {
      half8 hf = *reinterpret_cast<const half8*>(&lds_h[rb & 3][kt * 32 + kg8]);
      acc[kt & 3] = __builtin_amdgcn_mfma_f32_16x16x32_f16(wfrag[kt], hf,
                                                           acc[kt & 3], 0, 0, 0);
    }
    f32x4 s = (acc[0] + acc[1]) + (acc[2] + acc[3]);

    if (act) {
      union { u64 u; _Float16 h[4]; } pk;
      float hv[4];
#pragma unroll
      for (int r = 0; r < 4; ++r) {
        float v = s[r] + xpv[r];
        v = fminf(fmaxf(v, -15.f), 15.f);      // tanh saturated past +-9
        float e = __expf(2.f * v);
        hv[r] = (e - 1.f) / (e + 1.f);
        pk.h[r] = (_Float16)hv[r];
      }
      if (t < SEQ - 1) {
        _Float16* hnxt = hme + ((t + 1) & 1) * (GB * H);
        __hip_atomic_store(reinterpret_cast<u64*>(&hnxt[rb * H + colb]), pk.u,
                           __ATOMIC_RELAXED, __HIP_MEMORY_SCOPE_SYSTEM);
      }
      if (hs_out) {
        *reinterpret_cast<u64*>(
            &hs_out[((size_t)(b0 + rb) * SEQ + t) * H + colb]) = pk.u;
      } else if (t == SEQ - 1) {
        float4 o = {hv[0], hv[1], hv[2], hv[3]};
        *reinterpret_cast<float4*>(&h_last[(size_t)(b0 + rb) * H + colb]) = o;
      }
    }

    if (t < SEQ - 1) {
      // order: h stores globally visible BEFORE this WG's flag advances
      asm volatile("s_waitcnt vmcnt(0)" ::: "memory");
      __syncthreads();  // all 4 waves drained
      if (threadIdx.x == 0)
        __hip_atomic_store(&myflags[rank], (unsigned)(t + 1), __ATOMIC_RELAXED,
                           __HIP_MEMORY_SCOPE_SYSTEM);
    }
  }
}

// ---------------------------------------------------------------------------
// Final FC: out[b][n] = h_last[b] . W_fc[n] + b_fc[n], one wave per output.
// ---------------------------------------------------------------------------
__global__ __launch_bounds__(256) void fc_kernel(
    const float* __restrict__ h_last, const float* __restrict__ W_fc,
    const float* __restrict__ b_fc, float* __restrict__ out) {
  const int wave = threadIdx.x >> 6, lane = threadIdx.x & 63;
  const int o = blockIdx.x * 4 + wave;  // 0..8191
  const int b = o >> 7, n = o & 127;
  const float* hr = h_last + (size_t)b * H;
  const float* wr = W_fc + (size_t)n * H;
  float s = 0.0f;
  for (int k = lane; k < H; k += 64) s += hr[k] * wr[k];
#pragma unroll
  for (int off = 32; off; off >>= 1) s += __shfl_down(s, off);
  if (lane == 0) out[o] = s + b_fc[n];
}

// ---------------------------------------------------------------------------
extern "C" void kernel_launch(void* const* d_in, const int* in_sizes, int n_in,
                              void* d_out, int out_size, void* d_ws,
                              size_t ws_size, hipStream_t stream) {
  (void)in_sizes; (void)n_in; (void)out_size; (void)ws_size;
  const float* x     = (const float*)d_in[0];
  const float* W_ih0 = (const float*)d_in[1];
  const float* b_ih0 = (const float*)d_in[2];
  const float* W_hh0 = (const float*)d_in[3];
  const float* b_hh0 = (const float*)d_in[4];
  const float* W_ih1 = (const float*)d_in[5];
  const float* b_ih1 = (const float*)d_in[6];
  const float* W_hh1 = (const float*)d_in[7];
  const float* b_hh1 = (const float*)d_in[8];
  const float* W_fc  = (const float*)d_in[9];
  const float* b_fc  = (const float*)d_in[10];
  float* out = (float*)d_out;

  char* ws = (char*)d_ws;
  size_t off = 0;
  auto carve = [&](size_t bytes) {
    char* p = ws + off;
    off += (bytes + 255) & ~(size_t)255;
    return p;
  };
  float*    xpbuf   = (float*)   carve((size_t)MROWS * H * 4);  // 134 MB
  _Float16* hs0_16  = (_Float16*)carve((size_t)MROWS * H * 2);  //  67 MB
  _Float16* x16     = (_Float16*)carve((size_t)MROWS * NIN * 2);
  _Float16* wih0_16 = (_Float16*)carve((size_t)H * NIN * 2);
  _Float16* whh0_16 = (_Float16*)carve((size_t)H * H * 2);
  _Float16* wih1_16 = (_Float16*)carve((size_t)H * H * 2);
  _Float16* whh1_16 = (_Float16*)carve((size_t)H * H * 2);
  float*    bias0   = (float*)   carve(H * 4);
  float*    bias1   = (float*)   carve(H * 4);
  // zero region: [h16_0 | h16_1 | flags0 | flags1] contiguous (carve keeps
  // 256B alignment; all sizes are 256B multiples)
  _Float16* h16_0   = (_Float16*)carve((size_t)NCLUST * 2 * GB * H * 2);
  _Float16* h16_1   = (_Float16*)carve((size_t)NCLUST * 2 * GB * H * 2);
  unsigned* flags0  = (unsigned*)carve(NCLUST * 64 * 4);
  unsigned* flags1  = (unsigned*)carve(NCLUST * 64 * 4);
  float*    h_lastp = (float*)   carve((size_t)BATCH * H * 4);

  const int zero_words =
      (int)(((size_t)NCLUST * 2 * GB * H * 2 * 2 + NCLUST * 64 * 4 * 2) / 4);

  // 1. biases + zero h/flags
  init_misc_kernel<<<(zero_words + 255) / 256, 256, 0, stream>>>(
      b_ih0, b_hh0, b_ih1, b_hh1, bias0, bias1, (unsigned*)h16_0, zero_words);

  // 2. f16 conversions
  cvt16_kernel<<<(MROWS * NIN / 4 + 255) / 256, 256, 0, stream>>>(x, x16,
                                                                  MROWS * NIN / 4);
  cvt16_kernel<<<(H * NIN / 4 + 255) / 256, 256, 0, stream>>>(W_ih0, wih0_16,
                                                              H * NIN / 4);
  cvt16_kernel<<<(H * H / 4 + 255) / 256, 256, 0, stream>>>(W_hh0, whh0_16,
                                                            H * H / 4);
  cvt16_kernel<<<(H * H / 4 + 255) / 256, 256, 0, stream>>>(W_ih1, wih1_16,
                                                            H * H / 4);
  cvt16_kernel<<<(H * H / 4 + 255) / 256, 256, 0, stream>>>(W_hh1, whh1_16,
                                                            H * H / 4);

  // 3. xp0 = x @ W_ih0^T + (b_ih0 + b_hh0)
  {
    dim3 grid(MROWS / 128, H / 128);
    gemm_f16_kernel<<<grid, 256, 0, stream>>>(x16, wih0_16, bias0, xpbuf,
                                              MROWS, H, NIN);
  }

  // 4. layer-0 scan (cooperative: co-residency for spin polls)
  {
    const float* xp_p = xpbuf; const _Float16* w_p = whh0_16;
    _Float16* hb_p = h16_0; unsigned* f_p = flags0;
    _Float16* hs_p = hs0_16; float* hl_p = nullptr;
    void* args[] = {&xp_p, &w_p, &hb_p, &f_p, &hs_p, &hl_p};
    hipLaunchCooperativeKernel((const void*)scan_kernel, dim3(256), dim3(256),
                               args, 0, stream);
  }

  // 5. xp1 = hs0 @ W_ih1^T + (b_ih1 + b_hh1)   (reuses xpbuf)
  {
    dim3 grid(MROWS / 128, H / 128);
    gemm_f16_kernel<<<grid, 256, 0, stream>>>(hs0_16, wih1_16, bias1, xpbuf,
                                              MROWS, H, H);
  }

  // 6. layer-1 scan (keeps only final h)
  {
    const float* xp_p = xpbuf; const _Float16* w_p = whh1_16;
    _Float16* hb_p = h16_1; unsigned* f_p = flags1;
    _Float16* hs_p = nullptr; float* hl_p = h_lastp;
    void* args[] = {&xp_p, &w_p, &hb_p, &f_p, &hs_p, &hl_p};
    hipLaunchCooperativeKernel((const void*)scan_kernel, dim3(256), dim3(256),
                               args, 0, stream);
  }

  // 7. out = h_last @ W_fc^T + b_fc
  fc_kernel<<<BATCH * NOUT / 4, 256, 0, stream>>>(h_lastp, W_fc, b_fc, out);
}

// Round 3
// 2807.077 us; speedup vs baseline: 3.5921x; 1.2923x over previous
//
#include <hip/hip_runtime.h>
#include <hip/hip_fp16.h>

// Problem dims
#define H     1024
#define NIN   128
#define NOUT  128
#define BATCH 64
#define SEQ   512
#define MROWS (BATCH * SEQ)   // 32768

typedef _Float16 half8  __attribute__((ext_vector_type(8)));
typedef _Float16 half4v __attribute__((ext_vector_type(4)));
typedef float    f32x4  __attribute__((ext_vector_type(4)));
typedef unsigned long long u64;

// ---------------------------------------------------------------------------
// f32 -> f16 conversion (vectorized, 4 elems/thread)
// ---------------------------------------------------------------------------
__global__ void cvt16_kernel(const float* __restrict__ src,
                             _Float16* __restrict__ dst, int n4) {
  int i = blockIdx.x * blockDim.x + threadIdx.x;
  if (i < n4) {
    float4 v = reinterpret_cast<const float4*>(src)[i];
    half4v h = {(_Float16)v.x, (_Float16)v.y, (_Float16)v.z, (_Float16)v.w};
    *reinterpret_cast<half4v*>(dst + (size_t)i * 4) = h;
  }
}

// ---------------------------------------------------------------------------
// biases + zero h-unit ring buffers; ws is poisoned 0xAA before every timed
// call so this runs every call.
// ---------------------------------------------------------------------------
__global__ void init_misc_kernel(const float* __restrict__ b_ih0,
                                 const float* __restrict__ b_hh0,
                                 const float* __restrict__ b_ih1,
                                 const float* __restrict__ b_hh1,
                                 float* __restrict__ bias0,
                                 float* __restrict__ bias1,
                                 unsigned* __restrict__ zero_base,
                                 int zero_words) {
  int i = blockIdx.x * blockDim.x + threadIdx.x;
  if (i < H) {
    bias0[i] = b_ih0[i] + b_hh0[i];
    bias1[i] = b_ih1[i] + b_hh1[i];
  }
  for (int j = i; j < zero_words; j += gridDim.x * blockDim.x) zero_base[j] = 0u;
}

// ---------------------------------------------------------------------------
// Generic f16 MFMA GEMM, C[m][n] = sum_k A[m][k]*B[n][k] + bias[n]  (fp32 out)
// (unchanged — not the bottleneck)
// ---------------------------------------------------------------------------
__global__ __launch_bounds__(256) void gemm_f16_kernel(
    const _Float16* __restrict__ A, const _Float16* __restrict__ B,
    const float* __restrict__ bias, float* __restrict__ C,
    int M, int N, int K) {
  __shared__ _Float16 As[128][40];
  __shared__ _Float16 Bs[128][40];
  const int m0 = blockIdx.x * 128;
  const int n0 = blockIdx.y * 128;
  const int tid = threadIdx.x;
  const int wave = tid >> 6, lane = tid & 63;
  const int wm = (wave >> 1) * 64, wn = (wave & 1) * 64;
  const int fr = lane & 15;
  const int kg = (lane >> 4) * 8;

  f32x4 acc[4][4] = {};
  for (int k0 = 0; k0 < K; k0 += 32) {
    __syncthreads();
    for (int c = tid; c < 512; c += 256) {
      int row = c >> 2, ko = (c & 3) * 8;
      *reinterpret_cast<half8*>(&As[row][ko]) =
          *reinterpret_cast<const half8*>(&A[(size_t)(m0 + row) * K + k0 + ko]);
      *reinterpret_cast<half8*>(&Bs[row][ko]) =
          *reinterpret_cast<const half8*>(&B[(size_t)(n0 + row) * K + k0 + ko]);
    }
    __syncthreads();
    half8 af[4], bf[4];
#pragma unroll
    for (int i = 0; i < 4; ++i)
      af[i] = *reinterpret_cast<const half8*>(&As[wm + i * 16 + fr][kg]);
#pragma unroll
    for (int j = 0; j < 4; ++j)
      bf[j] = *reinterpret_cast<const half8*>(&Bs[wn + j * 16 + fr][kg]);
#pragma unroll
    for (int i = 0; i < 4; ++i)
#pragma unroll
      for (int j = 0; j < 4; ++j)
        acc[i][j] = __builtin_amdgcn_mfma_f32_16x16x32_f16(af[i], bf[j],
                                                           acc[i][j], 0, 0, 0);
  }
  const int lr = (lane >> 4) * 4, lc = lane & 15;
#pragma unroll
  for (int j = 0; j < 4; ++j) {
    int n = n0 + wn + j * 16 + lc;
    float bn = bias ? bias[n] : 0.0f;
#pragma unroll
    for (int i = 0; i < 4; ++i) {
      int m = m0 + wm + i * 16 + lr;
#pragma unroll
      for (int r = 0; r < 4; ++r)
        C[(size_t)(m + r) * N + n] = acc[i][j][r] + bn;
    }
  }
}

// ---------------------------------------------------------------------------
// Recurrent scan, fused data+tag sync.
//
// h is exchanged as 8B "units": lo32 = 2x f16 h values, hi32 = step tag.
// 8B aligned stores are single-copy atomic through the coherent fabric, so
// tag-valid => data-valid with NO fences/flags/vmcnt on the critical path.
// Depth-2 slot ring is safe: a consumer observing tag t+1 from WG B proves
// (by MFMA data dependence) B finished reading slot t-1 before storing.
//
// Unit index w = kt*64 + r*16 + g*4 + hf  encodes  h[r][kt*32 + g*8 + hf*2].
// Consumer LDS mirror: word w at byte 4w -> fragment read for (c=r, g, kt) at
// byte kt*256 + c*64 + g*16: the 16 unique 16B addrs tile all 32 banks
// exactly twice (2-way = free, m136) -> no bank conflicts.
//
// W_hh slice (64 cols x 1024) lives in VGPRs as MFMA A-fragments, pinned with
// an asm barrier so the compiler cannot rematerialize the loads inside the
// t-loop (R2's VGPR_Count=92 showed it did exactly that).
// ---------------------------------------------------------------------------
#define NCLUST 16
#define CWGS   16
#define GB     4
#define UNITS  2048   // 4 rows x 1024 halfs / 2 halfs per unit

__global__ __launch_bounds__(256, 1) void scan_kernel(
    const float* __restrict__ xp,      // [BATCH][SEQ][H] fp32
    const _Float16* __restrict__ W16,  // [H][H] row = out col, contiguous K
    u64* __restrict__ hbuf,            // [NCLUST][2][UNITS] (zeroed)
    _Float16* __restrict__ hs_out,     // layer0: [BATCH][SEQ][H] f16, else null
    float* __restrict__ h_last)        // layer1: [BATCH][H] f32, else null
{
  __shared__ unsigned lds_h[UNITS];    // 8KB, word w <-> unit w

  const int blk = blockIdx.x;
  const int cluster = blk & (NCLUST - 1);
  const int rank = blk >> 4;
  const int tid = threadIdx.x;
  const int wave = tid >> 6;
  const int lane = tid & 63;
  const int fr = lane & 15;
  const int g = lane >> 4;             // k-group 0..3
  const int kg8 = g * 8;
  const int wcol = rank * 64 + wave * 16;
  const int c0 = wcol + g * 4;         // this lane's 4 out cols
  const int rb = lane & 15;            // batch row (valid if <GB)
  const bool act = rb < GB;

  // W_hh A-fragment slice -> registers, pinned (asm output can't be remat'd)
  f32x4 wfrag[32];
#pragma unroll
  for (int kt = 0; kt < 32; ++kt) {
    wfrag[kt] = *reinterpret_cast<const f32x4*>(
        &W16[(size_t)(wcol + fr) * H + kt * 32 + kg8]);
    asm volatile("" : "+v"(wfrag[kt]));
  }

  u64* hcl = hbuf + (size_t)cluster * (2 * UNITS);
  const int b0 = cluster * GB;

  // producer unit index (fixed per lane): units w0, w0+1
  const int w0 = (c0 >> 5) * 64 + rb * 16 + (((c0 >> 3) & 3) << 2) +
                 ((c0 >> 1) & 3);
  // consumer unit bases (4 x 16B worth = units up+0,1 for each j)
  const int up0 = tid * 2;

  for (int t = 0; t < SEQ; ++t) {
    // xp prefetch (h-independent, hides HBM latency under the poll)
    float4 xpv = {0.f, 0.f, 0.f, 0.f};
    if (act)
      xpv = *reinterpret_cast<const float4*>(
          &xp[((size_t)(b0 + rb) * SEQ + t) * H + c0]);

    f32x4 s = {0.f, 0.f, 0.f, 0.f};
    if (t > 0) {
      // ---- fused poll + stage: wait until all 8 of my units carry tag t ----
      const u64* src = hcl + (t & 1) * UNITS;
      const unsigned tag = (unsigned)t;
      u64 a[8];
      while (true) {
#pragma unroll
        for (int j = 0; j < 4; ++j) {
          a[2 * j]     = __hip_atomic_load(&src[up0 + j * 512], __ATOMIC_RELAXED,
                                           __HIP_MEMORY_SCOPE_SYSTEM);
          a[2 * j + 1] = __hip_atomic_load(&src[up0 + j * 512 + 1],
                                           __ATOMIC_RELAXED,
                                           __HIP_MEMORY_SCOPE_SYSTEM);
        }
        bool ok = true;
#pragma unroll
        for (int j = 0; j < 8; ++j) ok &= ((unsigned)(a[j] >> 32) == tag);
        if (ok) break;
        __builtin_amdgcn_s_sleep(1);
      }
      // all waves past poll => all waves' step t-1 LDS reads retired
      __syncthreads();
#pragma unroll
      for (int j = 0; j < 4; ++j) {
        u64 pk = (u64)(unsigned)a[2 * j] | ((u64)(unsigned)a[2 * j + 1] << 32);
        *reinterpret_cast<u64*>(&lds_h[up0 + j * 512]) = pk;
      }
      __syncthreads();

      // ---- MFMA: D = W(64x1024) . h^T ----
      const char* lb = reinterpret_cast<const char*>(lds_h);
      f32x4 acc[4] = {{0.f, 0.f, 0.f, 0.f}, {0.f, 0.f, 0.f, 0.f},
                      {0.f, 0.f, 0.f, 0.f}, {0.f, 0.f, 0.f, 0.f}};
#pragma unroll
      for (int kt = 0; kt < 32; ++kt) {
        half8 hf = *reinterpret_cast<const half8*>(
            lb + kt * 256 + (rb & 3) * 64 + g * 16);
        acc[kt & 3] = __builtin_amdgcn_mfma_f32_16x16x32_f16(
            __builtin_bit_cast(half8, wfrag[kt]), hf, acc[kt & 3], 0, 0, 0);
      }
      s = (acc[0] + acc[1]) + (acc[2] + acc[3]);
    }

    if (act) {
      union { u64 u; _Float16 h[4]; unsigned w[2]; } pk;
      float hv[4];
#pragma unroll
      for (int r = 0; r < 4; ++r) {
        float v = s[r] + xpv[r];
        v = fminf(fmaxf(v, -15.f), 15.f);
        float e = __expf(2.f * v);
        hv[r] = (e - 1.f) / (e + 1.f);
        pk.h[r] = (_Float16)hv[r];
      }
      if (t < SEQ - 1) {
        u64* dst = hcl + ((t + 1) & 1) * UNITS;
        const u64 tag64 = ((u64)(unsigned)(t + 1)) << 32;
        __hip_atomic_store(&dst[w0],     (u64)pk.w[0] | tag64,
                           __ATOMIC_RELAXED, __HIP_MEMORY_SCOPE_SYSTEM);
        __hip_atomic_store(&dst[w0 + 1], (u64)pk.w[1] | tag64,
                           __ATOMIC_RELAXED, __HIP_MEMORY_SCOPE_SYSTEM);
      }
      if (hs_out) {
        *reinterpret_cast<u64*>(
            &hs_out[((size_t)(b0 + rb) * SEQ + t) * H + c0]) = pk.u;
      } else if (t == SEQ - 1) {
        float4 o = {hv[0], hv[1], hv[2], hv[3]};
        *reinterpret_cast<float4*>(&h_last[(size_t)(b0 + rb) * H + c0]) = o;
      }
    }
  }
}

// ---------------------------------------------------------------------------
// Final FC: out[b][n] = h_last[b] . W_fc[n] + b_fc[n], one wave per output.
// ---------------------------------------------------------------------------
__global__ __launch_bounds__(256) void fc_kernel(
    const float* __restrict__ h_last, const float* __restrict__ W_fc,
    const float* __restrict__ b_fc, float* __restrict__ out) {
  const int wave = threadIdx.x >> 6, lane = threadIdx.x & 63;
  const int o = blockIdx.x * 4 + wave;  // 0..8191
  const int b = o >> 7, n = o & 127;
  const float* hr = h_last + (size_t)b * H;
  const float* wr = W_fc + (size_t)n * H;
  float s = 0.0f;
  for (int k = lane; k < H; k += 64) s += hr[k] * wr[k];
#pragma unroll
  for (int off = 32; off; off >>= 1) s += __shfl_down(s, off);
  if (lane == 0) out[o] = s + b_fc[n];
}

// ---------------------------------------------------------------------------
extern "C" void kernel_launch(void* const* d_in, const int* in_sizes, int n_in,
                              void* d_out, int out_size, void* d_ws,
                              size_t ws_size, hipStream_t stream) {
  (void)in_sizes; (void)n_in; (void)out_size; (void)ws_size;
  const float* x     = (const float*)d_in[0];
  const float* W_ih0 = (const float*)d_in[1];
  const float* b_ih0 = (const float*)d_in[2];
  const float* W_hh0 = (const float*)d_in[3];
  const float* b_hh0 = (const float*)d_in[4];
  const float* W_ih1 = (const float*)d_in[5];
  const float* b_ih1 = (const float*)d_in[6];
  const float* W_hh1 = (const float*)d_in[7];
  const float* b_hh1 = (const float*)d_in[8];
  const float* W_fc  = (const float*)d_in[9];
  const float* b_fc  = (const float*)d_in[10];
  float* out = (float*)d_out;

  char* ws = (char*)d_ws;
  size_t off = 0;
  auto carve = [&](size_t bytes) {
    char* p = ws + off;
    off += (bytes + 255) & ~(size_t)255;
    return p;
  };
  float*    xpbuf   = (float*)   carve((size_t)MROWS * H * 4);  // 134 MB
  _Float16* hs0_16  = (_Float16*)carve((size_t)MROWS * H * 2);  //  67 MB
  _Float16* x16     = (_Float16*)carve((size_t)MROWS * NIN * 2);
  _Float16* wih0_16 = (_Float16*)carve((size_t)H * NIN * 2);
  _Float16* whh0_16 = (_Float16*)carve((size_t)H * H * 2);
  _Float16* wih1_16 = (_Float16*)carve((size_t)H * H * 2);
  _Float16* whh1_16 = (_Float16*)carve((size_t)H * H * 2);
  float*    bias0   = (float*)   carve(H * 4);
  float*    bias1   = (float*)   carve(H * 4);
  // zero region: [hb0 | hb1] contiguous (each 16 clusters x 2 slots x 16KB)
  u64*      hb0     = (u64*)     carve((size_t)NCLUST * 2 * UNITS * 8);
  u64*      hb1     = (u64*)     carve((size_t)NCLUST * 2 * UNITS * 8);
  float*    h_lastp = (float*)   carve((size_t)BATCH * H * 4);

  const int zero_words = (int)((size_t)NCLUST * 2 * UNITS * 8 * 2 / 4);

  // 1. biases + zero h rings
  init_misc_kernel<<<(zero_words + 255) / 256, 256, 0, stream>>>(
      b_ih0, b_hh0, b_ih1, b_hh1, bias0, bias1, (unsigned*)hb0, zero_words);

  // 2. f16 conversions
  cvt16_kernel<<<(MROWS * NIN / 4 + 255) / 256, 256, 0, stream>>>(x, x16,
                                                                  MROWS * NIN / 4);
  cvt16_kernel<<<(H * NIN / 4 + 255) / 256, 256, 0, stream>>>(W_ih0, wih0_16,
                                                              H * NIN / 4);
  cvt16_kernel<<<(H * H / 4 + 255) / 256, 256, 0, stream>>>(W_hh0, whh0_16,
                                                            H * H / 4);
  cvt16_kernel<<<(H * H / 4 + 255) / 256, 256, 0, stream>>>(W_ih1, wih1_16,
                                                            H * H / 4);
  cvt16_kernel<<<(H * H / 4 + 255) / 256, 256, 0, stream>>>(W_hh1, whh1_16,
                                                            H * H / 4);

  // 3. xp0 = x @ W_ih0^T + (b_ih0 + b_hh0)
  {
    dim3 grid(MROWS / 128, H / 128);
    gemm_f16_kernel<<<grid, 256, 0, stream>>>(x16, wih0_16, bias0, xpbuf,
                                              MROWS, H, NIN);
  }

  // 4. layer-0 scan
  {
    const float* xp_p = xpbuf; const _Float16* w_p = whh0_16;
    u64* hb_p = hb0; _Float16* hs_p = hs0_16; float* hl_p = nullptr;
    void* args[] = {&xp_p, &w_p, &hb_p, &hs_p, &hl_p};
    hipLaunchCooperativeKernel((const void*)scan_kernel, dim3(256), dim3(256),
                               args, 0, stream);
  }

  // 5. xp1 = hs0 @ W_ih1^T + (b_ih1 + b_hh1)
  {
    dim3 grid(MROWS / 128, H / 128);
    gemm_f16_kernel<<<grid, 256, 0, stream>>>(hs0_16, wih1_16, bias1, xpbuf,
                                              MROWS, H, H);
  }

  // 6. layer-1 scan (keeps only final h)
  {
    const float* xp_p = xpbuf; const _Float16* w_p = whh1_16;
    u64* hb_p = hb1; _Float16* hs_p = nullptr; float* hl_p = h_lastp;
    void* args[] = {&xp_p, &w_p, &hb_p, &hs_p, &hl_p};
    hipLaunchCooperativeKernel((const void*)scan_kernel, dim3(256), dim3(256),
                               args, 0, stream);
  }

  // 7. out = h_last @ W_fc^T + b_fc
  fc_kernel<<<BATCH * NOUT / 4, 256, 0, stream>>>(h_lastp, W_fc, b_fc, out);
}

// Round 4
// 1990.378 us; speedup vs baseline: 5.0660x; 1.4103x over previous
//
#include <hip/hip_runtime.h>
#include <hip/hip_fp16.h>

// Problem dims
#define H     1024
#define NIN   128
#define NOUT  128
#define BATCH 64
#define SEQ   512
#define MROWS (BATCH * SEQ)   // 32768

typedef _Float16 half8  __attribute__((ext_vector_type(8)));
typedef _Float16 half4v __attribute__((ext_vector_type(4)));
typedef float    f32x4  __attribute__((ext_vector_type(4)));
typedef unsigned uint4v __attribute__((ext_vector_type(4)));
typedef unsigned long long u64;

// ---------------------------------------------------------------------------
// f32 -> f16 conversion (vectorized, 4 elems/thread)
// ---------------------------------------------------------------------------
__global__ void cvt16_kernel(const float* __restrict__ src,
                             _Float16* __restrict__ dst, int n4) {
  int i = blockIdx.x * blockDim.x + threadIdx.x;
  if (i < n4) {
    float4 v = reinterpret_cast<const float4*>(src)[i];
    half4v h = {(_Float16)v.x, (_Float16)v.y, (_Float16)v.z, (_Float16)v.w};
    *reinterpret_cast<half4v*>(dst + (size_t)i * 4) = h;
  }
}

// ---------------------------------------------------------------------------
// biases + zero the 4 ring buffers; ws is poisoned 0xAA before every timed
// call so this runs every call. (Tags only match real stores, but zeroing
// keeps the rings clean.)
// ---------------------------------------------------------------------------
__global__ void init_misc_kernel(const float* __restrict__ b_ih0,
                                 const float* __restrict__ b_hh0,
                                 const float* __restrict__ b_ih1,
                                 const float* __restrict__ b_hh1,
                                 float* __restrict__ bias0,
                                 float* __restrict__ bias1,
                                 unsigned* __restrict__ zero_base,
                                 int zero_words) {
  int i = blockIdx.x * blockDim.x + threadIdx.x;
  if (i < H) {
    bias0[i] = b_ih0[i] + b_hh0[i];
    bias1[i] = b_ih1[i] + b_hh1[i];
  }
  for (int j = i; j < zero_words; j += gridDim.x * blockDim.x) zero_base[j] = 0u;
}

// ---------------------------------------------------------------------------
// Generic f16 MFMA GEMM, C[m][n] = sum_k A[m][k]*B[n][k] + bias[n]  (fp32 out)
// (unchanged — not the bottleneck)
// ---------------------------------------------------------------------------
__global__ __launch_bounds__(256) void gemm_f16_kernel(
    const _Float16* __restrict__ A, const _Float16* __restrict__ B,
    const float* __restrict__ bias, float* __restrict__ C,
    int M, int N, int K) {
  __shared__ _Float16 As[128][40];
  __shared__ _Float16 Bs[128][40];
  const int m0 = blockIdx.x * 128;
  const int n0 = blockIdx.y * 128;
  const int tid = threadIdx.x;
  const int wave = tid >> 6, lane = tid & 63;
  const int wm = (wave >> 1) * 64, wn = (wave & 1) * 64;
  const int fr = lane & 15;
  const int kg = (lane >> 4) * 8;

  f32x4 acc[4][4] = {};
  for (int k0 = 0; k0 < K; k0 += 32) {
    __syncthreads();
    for (int c = tid; c < 512; c += 256) {
      int row = c >> 2, ko = (c & 3) * 8;
      *reinterpret_cast<half8*>(&As[row][ko]) =
          *reinterpret_cast<const half8*>(&A[(size_t)(m0 + row) * K + k0 + ko]);
      *reinterpret_cast<half8*>(&Bs[row][ko]) =
          *reinterpret_cast<const half8*>(&B[(size_t)(n0 + row) * K + k0 + ko]);
    }
    __syncthreads();
    half8 af[4], bf[4];
#pragma unroll
    for (int i = 0; i < 4; ++i)
      af[i] = *reinterpret_cast<const half8*>(&As[wm + i * 16 + fr][kg]);
#pragma unroll
    for (int j = 0; j < 4; ++j)
      bf[j] = *reinterpret_cast<const half8*>(&Bs[wn + j * 16 + fr][kg]);
#pragma unroll
    for (int i = 0; i < 4; ++i)
#pragma unroll
      for (int j = 0; j < 4; ++j)
        acc[i][j] = __builtin_amdgcn_mfma_f32_16x16x32_f16(af[i], bf[j],
                                                           acc[i][j], 0, 0, 0);
  }
  const int lr = (lane >> 4) * 4, lc = lane & 15;
#pragma unroll
  for (int j = 0; j < 4; ++j) {
    int n = n0 + wn + j * 16 + lc;
    float bn = bias ? bias[n] : 0.0f;
#pragma unroll
    for (int i = 0; i < 4; ++i) {
      int m = m0 + wm + i * 16 + lr;
#pragma unroll
      for (int r = 0; r < 4; ++r)
        C[(size_t)(m + r) * N + n] = acc[i][j][r] + bn;
    }
  }
}

// ---------------------------------------------------------------------------
// Recurrent scan, topology-adaptive dual-ring data+tag sync.
//
// Units: 8B = (lo32: 2x f16 h | hi32: step tag). 8B aligned stores are
// single-copy atomic -> tag-valid => data-valid. Tags are monotone per slot,
// so a stale read can only show an OLDER tag (never a false positive).
//
// Producer stores each unit pair (16B dwordx4) TWICE:
//   fast ring: sc0 only  -> dirties the producer's L2; same-XCD consumers
//              (cluster = blk&15 is same-XCD under round-robin dispatch) see
//              it at L2 latency.
//   slow ring: sc0 sc1   -> system-visible (R3-proven), cross-XCD fallback.
// Consumer polls fast ring with sc0+nt loads (L1-bypass, no L2 allocate =>
// no stale-allocated-line trap) for 4 iterations, then falls back to slow
// ring sc0 sc1 polls. Correctness/liveness placement-independent; only
// speed depends on the WG->XCD mapping.
//
// Depth-2 slot ring safety: a producer stores tag t+2 into slot t&1 only
// after seeing ALL tag-t+1 units, which requires every WG (incl. us) to have
// finished consuming slot t&1 (our t+1 store happens after our barrier-
// protected LDS stage of slot t&1). So mid-poll overwrite is impossible.
// ---------------------------------------------------------------------------
#define NCLUST 16
#define CWGS   16
#define GB     4
#define UNITS  2048   // 4 rows x 1024 halfs / 2 halfs per unit

__global__ __launch_bounds__(256, 1) void scan_kernel(
    const float* __restrict__ xp,      // [BATCH][SEQ][H] fp32
    const _Float16* __restrict__ W16,  // [H][H] row = out col, contiguous K
    u64* __restrict__ fastbuf,         // [NCLUST][2][UNITS] (zeroed)
    u64* __restrict__ slowbuf,         // [NCLUST][2][UNITS] (zeroed)
    _Float16* __restrict__ hs_out,     // layer0: [BATCH][SEQ][H] f16, else null
    float* __restrict__ h_last)        // layer1: [BATCH][H] f32, else null
{
  __shared__ unsigned lds_h[2][UNITS];   // 16KB double buffer

  const int blk = blockIdx.x;
  const int cluster = blk & (NCLUST - 1);
  const int rank = blk >> 4;
  const int tid = threadIdx.x;
  const int wave = tid >> 6;
  const int lane = tid & 63;
  const int fr = lane & 15;
  const int g = lane >> 4;             // k-group 0..3
  const int kg8 = g * 8;
  const int wcol = rank * 64 + wave * 16;
  const int c0 = wcol + g * 4;         // this lane's 4 out cols
  const int rb = lane & 15;            // batch row (valid if <GB)
  const bool act = rb < GB;

  // W_hh A-fragment slice -> registers (lands in AGPRs; MFMA reads them)
  f32x4 wfrag[32];
#pragma unroll
  for (int kt = 0; kt < 32; ++kt) {
    wfrag[kt] = *reinterpret_cast<const f32x4*>(
        &W16[(size_t)(wcol + fr) * H + kt * 32 + kg8]);
    asm volatile("" : "+v"(wfrag[kt]));
  }

  u64* fcl = fastbuf + (size_t)cluster * (2 * UNITS);
  u64* scl = slowbuf + (size_t)cluster * (2 * UNITS);
  const int b0 = cluster * GB;

  // producer unit index (even => 16B-aligned pair {w0, w0+1})
  const int w0 = (c0 >> 5) * 64 + rb * 16 + (((c0 >> 3) & 3) << 2) +
                 ((c0 >> 1) & 3);

  // xp prefetch, one step ahead (latency fully hidden under previous step)
  float4 xpv = {0.f, 0.f, 0.f, 0.f};
  if (act)
    xpv = *reinterpret_cast<const float4*>(
        &xp[((size_t)(b0 + rb) * SEQ + 0) * H + c0]);

  for (int t = 0; t < SEQ; ++t) {
    uint4v q0, q1, q2, q3;
    if (t > 0) {
      // ---- poll: wait until my 4x16B of units carry tag t ----
      const char* fb = (const char*)(fcl + (t & 1) * UNITS) + (size_t)tid * 16;
      const char* sb = (const char*)(scl + (t & 1) * UNITS) + (size_t)tid * 16;
      const unsigned tag = (unsigned)t;
      int it = 0;
      while (true) {
        if (it < 4) {
          asm volatile(
              "global_load_dwordx4 %0, %4, off sc0 nt\n\t"
              "global_load_dwordx4 %1, %5, off sc0 nt\n\t"
              "global_load_dwordx4 %2, %6, off sc0 nt\n\t"
              "global_load_dwordx4 %3, %7, off sc0 nt\n\t"
              "s_waitcnt vmcnt(0)"
              : "=&v"(q0), "=&v"(q1), "=&v"(q2), "=&v"(q3)
              : "v"(fb), "v"(fb + 4096), "v"(fb + 8192), "v"(fb + 12288)
              : "memory");
        } else {
          asm volatile(
              "global_load_dwordx4 %0, %4, off sc0 sc1\n\t"
              "global_load_dwordx4 %1, %5, off sc0 sc1\n\t"
              "global_load_dwordx4 %2, %6, off sc0 sc1\n\t"
              "global_load_dwordx4 %3, %7, off sc0 sc1\n\t"
              "s_waitcnt vmcnt(0)"
              : "=&v"(q0), "=&v"(q1), "=&v"(q2), "=&v"(q3)
              : "v"(sb), "v"(sb + 4096), "v"(sb + 8192), "v"(sb + 12288)
              : "memory");
        }
        bool ok = (q0.y == tag) & (q0.w == tag) & (q1.y == tag) &
                  (q1.w == tag) & (q2.y == tag) & (q2.w == tag) &
                  (q3.y == tag) & (q3.w == tag);
        if (__ballot(ok) == ~0ull) break;
        ++it;
        if (it > 4) __builtin_amdgcn_s_sleep(1);
      }
    }

    // issue next step's xp prefetch now (hidden under LDS+MFMA+epilogue)
    float4 xpn = {0.f, 0.f, 0.f, 0.f};
    {
      int t2 = (t + 1 < SEQ) ? (t + 1) : (SEQ - 1);
      if (act)
        xpn = *reinterpret_cast<const float4*>(
            &xp[((size_t)(b0 + rb) * SEQ + t2) * H + c0]);
    }

    f32x4 s = {0.f, 0.f, 0.f, 0.f};
    if (t > 0) {
      // stage polled units to LDS (double-buffered: no pre-barrier needed)
      unsigned* lb_w = lds_h[t & 1];
#pragma unroll
      for (int j = 0; j < 4; ++j) {
        uint4v q = (j == 0) ? q0 : (j == 1) ? q1 : (j == 2) ? q2 : q3;
        u64 pk = (u64)q.x | ((u64)q.z << 32);
        *reinterpret_cast<u64*>(&lb_w[tid * 2 + j * 512]) = pk;
      }
      __syncthreads();

      // ---- MFMA: D = W(64x1024) . h^T ----
      const char* lb = reinterpret_cast<const char*>(lds_h[t & 1]);
      f32x4 acc[4] = {{0.f, 0.f, 0.f, 0.f}, {0.f, 0.f, 0.f, 0.f},
                      {0.f, 0.f, 0.f, 0.f}, {0.f, 0.f, 0.f, 0.f}};
#pragma unroll
      for (int kt = 0; kt < 32; ++kt) {
        half8 hf = *reinterpret_cast<const half8*>(
            lb + kt * 256 + (rb & 3) * 64 + g * 16);
        acc[kt & 3] = __builtin_amdgcn_mfma_f32_16x16x32_f16(
            __builtin_bit_cast(half8, wfrag[kt]), hf, acc[kt & 3], 0, 0, 0);
      }
      s = (acc[0] + acc[1]) + (acc[2] + acc[3]);
    }

    if (act) {
      union { u64 u; _Float16 h[4]; unsigned w[2]; } pk;
      float hv[4];
#pragma unroll
      for (int r = 0; r < 4; ++r) {
        float v = s[r] + xpv[r];
        v = fminf(fmaxf(v, -15.f), 15.f);
        float e = __expf(2.f * v);                       // e = exp(2v)
        hv[r] = 1.f - 2.f * __builtin_amdgcn_rcpf(e + 1.f);  // tanh(v)
        pk.h[r] = (_Float16)hv[r];
      }
      if (t < SEQ - 1) {
        const unsigned tagw = (unsigned)(t + 1);
        uint4v sv = {pk.w[0], tagw, pk.w[1], tagw};
        u64* fdst = fcl + ((t + 1) & 1) * UNITS + w0;
        u64* sdst = scl + ((t + 1) & 1) * UNITS + w0;
        asm volatile(
            "global_store_dwordx4 %0, %2, off sc0\n\t"
            "global_store_dwordx4 %1, %2, off sc0 sc1"
            :: "v"(fdst), "v"(sdst), "v"(sv)
            : "memory");
      }
      if (hs_out) {
        *reinterpret_cast<u64*>(
            &hs_out[((size_t)(b0 + rb) * SEQ + t) * H + c0]) = pk.u;
      } else if (t == SEQ - 1) {
        float4 o = {hv[0], hv[1], hv[2], hv[3]};
        *reinterpret_cast<float4*>(&h_last[(size_t)(b0 + rb) * H + c0]) = o;
      }
    }
    xpv = xpn;
  }
}

// ---------------------------------------------------------------------------
// Final FC: out[b][n] = h_last[b] . W_fc[n] + b_fc[n], one wave per output.
// ---------------------------------------------------------------------------
__global__ __launch_bounds__(256) void fc_kernel(
    const float* __restrict__ h_last, const float* __restrict__ W_fc,
    const float* __restrict__ b_fc, float* __restrict__ out) {
  const int wave = threadIdx.x >> 6, lane = threadIdx.x & 63;
  const int o = blockIdx.x * 4 + wave;  // 0..8191
  const int b = o >> 7, n = o & 127;
  const float* hr = h_last + (size_t)b * H;
  const float* wr = W_fc + (size_t)n * H;
  float s = 0.0f;
  for (int k = lane; k < H; k += 64) s += hr[k] * wr[k];
#pragma unroll
  for (int off = 32; off; off >>= 1) s += __shfl_down(s, off);
  if (lane == 0) out[o] = s + b_fc[n];
}

// ---------------------------------------------------------------------------
extern "C" void kernel_launch(void* const* d_in, const int* in_sizes, int n_in,
                              void* d_out, int out_size, void* d_ws,
                              size_t ws_size, hipStream_t stream) {
  (void)in_sizes; (void)n_in; (void)out_size; (void)ws_size;
  const float* x     = (const float*)d_in[0];
  const float* W_ih0 = (const float*)d_in[1];
  const float* b_ih0 = (const float*)d_in[2];
  const float* W_hh0 = (const float*)d_in[3];
  const float* b_hh0 = (const float*)d_in[4];
  const float* W_ih1 = (const float*)d_in[5];
  const float* b_ih1 = (const float*)d_in[6];
  const float* W_hh1 = (const float*)d_in[7];
  const float* b_hh1 = (const float*)d_in[8];
  const float* W_fc  = (const float*)d_in[9];
  const float* b_fc  = (const float*)d_in[10];
  float* out = (float*)d_out;

  char* ws = (char*)d_ws;
  size_t off = 0;
  auto carve = [&](size_t bytes) {
    char* p = ws + off;
    off += (bytes + 255) & ~(size_t)255;
    return p;
  };
  float*    xpbuf   = (float*)   carve((size_t)MROWS * H * 4);  // 134 MB
  _Float16* hs0_16  = (_Float16*)carve((size_t)MROWS * H * 2);  //  67 MB
  _Float16* x16     = (_Float16*)carve((size_t)MROWS * NIN * 2);
  _Float16* wih0_16 = (_Float16*)carve((size_t)H * NIN * 2);
  _Float16* whh0_16 = (_Float16*)carve((size_t)H * H * 2);
  _Float16* wih1_16 = (_Float16*)carve((size_t)H * H * 2);
  _Float16* whh1_16 = (_Float16*)carve((size_t)H * H * 2);
  float*    bias0   = (float*)   carve(H * 4);
  float*    bias1   = (float*)   carve(H * 4);
  // zero region: [fb0 | fb1 | sb0 | sb1] contiguous, 512KB each
  const size_t RING = (size_t)NCLUST * 2 * UNITS * 8;
  u64*      fb0     = (u64*)     carve(RING);
  u64*      fb1     = (u64*)     carve(RING);
  u64*      sb0     = (u64*)     carve(RING);
  u64*      sb1     = (u64*)     carve(RING);
  float*    h_lastp = (float*)   carve((size_t)BATCH * H * 4);

  const int zero_words = (int)(RING * 4 / 4);

  // 1. biases + zero rings
  init_misc_kernel<<<(zero_words + 255) / 256, 256, 0, stream>>>(
      b_ih0, b_hh0, b_ih1, b_hh1, bias0, bias1, (unsigned*)fb0, zero_words);

  // 2. f16 conversions
  cvt16_kernel<<<(MROWS * NIN / 4 + 255) / 256, 256, 0, stream>>>(x, x16,
                                                                  MROWS * NIN / 4);
  cvt16_kernel<<<(H * NIN / 4 + 255) / 256, 256, 0, stream>>>(W_ih0, wih0_16,
                                                              H * NIN / 4);
  cvt16_kernel<<<(H * H / 4 + 255) / 256, 256, 0, stream>>>(W_hh0, whh0_16,
                                                            H * H / 4);
  cvt16_kernel<<<(H * H / 4 + 255) / 256, 256, 0, stream>>>(W_ih1, wih1_16,
                                                            H * H / 4);
  cvt16_kernel<<<(H * H / 4 + 255) / 256, 256, 0, stream>>>(W_hh1, whh1_16,
                                                            H * H / 4);

  // 3. xp0 = x @ W_ih0^T + (b_ih0 + b_hh0)
  {
    dim3 grid(MROWS / 128, H / 128);
    gemm_f16_kernel<<<grid, 256, 0, stream>>>(x16, wih0_16, bias0, xpbuf,
                                              MROWS, H, NIN);
  }

  // 4. layer-0 scan
  {
    const float* xp_p = xpbuf; const _Float16* w_p = whh0_16;
    u64* fb_p = fb0; u64* sb_p = sb0;
    _Float16* hs_p = hs0_16; float* hl_p = nullptr;
    void* args[] = {&xp_p, &w_p, &fb_p, &sb_p, &hs_p, &hl_p};
    hipLaunchCooperativeKernel((const void*)scan_kernel, dim3(256), dim3(256),
                               args, 0, stream);
  }

  // 5. xp1 = hs0 @ W_ih1^T + (b_ih1 + b_hh1)
  {
    dim3 grid(MROWS / 128, H / 128);
    gemm_f16_kernel<<<grid, 256, 0, stream>>>(hs0_16, wih1_16, bias1, xpbuf,
                                              MROWS, H, H);
  }

  // 6. layer-1 scan (keeps only final h)
  {
    const float* xp_p = xpbuf; const _Float16* w_p = whh1_16;
    u64* fb_p = fb1; u64* sb_p = sb1;
    _Float16* hs_p = nullptr; float* hl_p = h_lastp;
    void* args[] = {&xp_p, &w_p, &fb_p, &sb_p, &hs_p, &hl_p};
    hipLaunchCooperativeKernel((const void*)scan_kernel, dim3(256), dim3(256),
                               args, 0, stream);
  }

  // 7. out = h_last @ W_fc^T + b_fc
  fc_kernel<<<BATCH * NOUT / 4, 256, 0, stream>>>(h_lastp, W_fc, b_fc, out);
}